// Round 12
// baseline (192.464 us; speedup 1.0000x reference)
//
#include <hip/hip_runtime.h>

// Problem constants (inputs: (32,64,32,32) fp32; embed: (64,1024) fp32)
#define N_PIX  32768   // B*H*W
#define C_DIM  64
#define K_EMB  1024
#define HW     1024    // H*W
#define P_TILE 8       // pixels per block
#define NBLK   (N_PIX / P_TILE)   // 4096

// d_out layout (float32, concatenated in return order):
//   quantized_out (B,C,H,W) | loss | encoding_indices | perplexity
#define OUT_Q_OFF    0
#define OUT_LOSS_OFF 2097152
#define OUT_IDX_OFF  2097153
#define OUT_PERP_OFF 2129921

// ws layout: counts[1024] u32 @0 | lossAcc f32 @4096 | e2[1024] f32 @8192
// Lessons encoded:
//  - r9: NO __threadfence in the grid kernel (per-XCD L2 writeback storm).
//  - r10: NO `#pragma unroll >1` on the c-loop (doubles ALL live ranges ->
//    scratch spill). This round pipelines MANUALLY (E/F set role-swap) so only
//    the e-registers double (they already did, as N-regs) and no movs remain.
//  - r1/r5: accumulators must be NAMED float4s, no address-taking.
//  - r4: no SMEM (s_load) feeds in the hot loop (OOO returns -> lgkmcnt(0) drains).
//  - overhead model (r2..r11): bench fixed cost ~50us regardless of op count.

__device__ __forceinline__ unsigned long long pack_score(float d, int k) {
    unsigned int u = __float_as_uint(d);
    u = (u & 0x80000000u) ? ~u : (u | 0x80000000u);  // monotone map, negative-safe
    return ((unsigned long long)u << 32) | (unsigned int)k;
}

__global__ void k_e2(const float* __restrict__ embed, float* __restrict__ e2) {
    int k = blockIdx.x * blockDim.x + threadIdx.x;  // 0..1023
    float s = 0.f;
#pragma unroll
    for (int c = 0; c < C_DIM; ++c) {
        float v = embed[c * K_EMB + k];
        s = fmaf(v, v, s);
    }
    e2[k] = s;
}

// k-major cooperative kernel: 128 threads; thread owns 8 k's (quads kL=4*tid,
// kH=512+4*tid, float4-coalesced); 8 pixels/block staged in LDS (broadcast
// ds_read_b128). Hot loop = pure MACs: ee hoisted to k_e2, rotation movs
// eliminated by a two-phase (E-set/F-set) manually software-pipelined loop.
__global__ __launch_bounds__(128, 4) void k_main(
    const float* __restrict__ inp, const float* __restrict__ embed,
    const float* __restrict__ e2, unsigned int* __restrict__ counts,
    float* __restrict__ lossAcc, float* __restrict__ out_q,
    float* __restrict__ out_idx) {
    __shared__ float x_lds[C_DIM * P_TILE];           // 2 KB
    __shared__ unsigned long long red[2][P_TILE];
    __shared__ int ksel[P_TILE];
    __shared__ float lred[2];

    const int tid = threadIdx.x;                      // 0..127
    const int n0  = blockIdx.x * P_TILE;
    const int b   = n0 >> 10;
    const int hw0 = n0 & 1023;
    const float* __restrict__ xu = inp + b * (C_DIM * HW) + hw0;

    // stage x tile: 128 threads -> (c = tid>>1, one float4 half-row)
    {
        const int c  = tid >> 1;
        const int p4 = (tid & 1) * 4;
        *reinterpret_cast<float4*>(&x_lds[c * P_TILE + p4]) =
            *reinterpret_cast<const float4*>(xu + c * HW + p4);
    }
    __syncthreads();

    const int kL = tid * 4;            // low-half quad
    const int kH = 512 + tid * 4;      // high-half quad
    const float4* __restrict__ ebL = reinterpret_cast<const float4*>(embed) + tid;
    const float4* __restrict__ ebH = ebL + 128;   // +512 floats; row stride 256 float4

    float4 aL0={0,0,0,0},aL1={0,0,0,0},aL2={0,0,0,0},aL3={0,0,0,0};
    float4 aL4={0,0,0,0},aL5={0,0,0,0},aL6={0,0,0,0},aL7={0,0,0,0};
    float4 aH0={0,0,0,0},aH1={0,0,0,0},aH2={0,0,0,0},aH3={0,0,0,0};
    float4 aH4={0,0,0,0},aH5={0,0,0,0},aH6={0,0,0,0},aH7={0,0,0,0};

#define FMA8(i, xv, EL, EH) \
    aL##i.x = fmaf((xv), EL.x, aL##i.x); aL##i.y = fmaf((xv), EL.y, aL##i.y); \
    aL##i.z = fmaf((xv), EL.z, aL##i.z); aL##i.w = fmaf((xv), EL.w, aL##i.w); \
    aH##i.x = fmaf((xv), EH.x, aH##i.x); aH##i.y = fmaf((xv), EH.y, aH##i.y); \
    aH##i.z = fmaf((xv), EH.z, aH##i.z); aH##i.w = fmaf((xv), EH.w, aH##i.w);

#define BODY(EL, EH, A, B) { \
    FMA8(0, A.x, EL, EH) FMA8(1, A.y, EL, EH) \
    FMA8(2, A.z, EL, EH) FMA8(3, A.w, EL, EH) \
    FMA8(4, B.x, EL, EH) FMA8(5, B.y, EL, EH) \
    FMA8(6, B.z, EL, EH) FMA8(7, B.w, EL, EH) }

#define LDX(dst, c) dst = *reinterpret_cast<const float4*>(&x_lds[(c) * P_TILE])
#define LDX2(dA, dB, c) { LDX(dA, c); \
    dB = *reinterpret_cast<const float4*>(&x_lds[(c) * P_TILE + 4]); }

    float4 EL0 = ebL[0],   EH0 = ebH[0];     // e[c+0]
    float4 EL1 = ebL[256], EH1 = ebH[256];   // e[c+1]
    float4 XA, XB, YA, YB;
    LDX2(XA, XB, 0);

#pragma unroll 1
    for (int c = 0; c < C_DIM; c += 4) {
        // phase 0: compute c, c+1 on E set; prefetch e[c+2],e[c+3] into F set
        float4 FL0 = ebL[(c + 2) * 256], FH0 = ebH[(c + 2) * 256];
        float4 FL1 = ebL[(c + 3) * 256], FH1 = ebH[(c + 3) * 256];
        LDX2(YA, YB, c + 1);
        BODY(EL0, EH0, XA, XB)
        LDX2(XA, XB, c + 2);
        BODY(EL1, EH1, YA, YB)
        // phase 1: compute c+2, c+3 on F set; prefetch e[c+4],e[c+5] into E set
        const int c4 = (c + 4) & 63, c5 = (c + 5) & 63;   // tail-safe wrap
        EL0 = ebL[c4 * 256]; EH0 = ebH[c4 * 256];
        EL1 = ebL[c5 * 256]; EH1 = ebH[c5 * 256];
        LDX2(YA, YB, c + 3);
        BODY(FL0, FH0, XA, XB)
        LDX2(XA, XB, c4);
        BODY(FL1, FH1, YA, YB)
    }
#undef LDX2
#undef LDX
#undef BODY
#undef FMA8

    // load precomputed ||e||^2 for this thread's 8 codes (coalesced float4)
    const float4 eeL = reinterpret_cast<const float4*>(e2)[tid];
    const float4 eeH = reinterpret_cast<const float4*>(e2)[tid + 128];

    // per-pixel packed argmin: 8 candidate k's per thread, then 2-wave reduce
    const int wv = tid >> 6, ln = tid & 63;
#define RED_P(i) { \
        const float s0 = fmaf(-2.f, aL##i.x, eeL.x); \
        const float s1 = fmaf(-2.f, aL##i.y, eeL.y); \
        const float s2 = fmaf(-2.f, aL##i.z, eeL.z); \
        const float s3 = fmaf(-2.f, aL##i.w, eeL.w); \
        const float s4 = fmaf(-2.f, aH##i.x, eeH.x); \
        const float s5 = fmaf(-2.f, aH##i.y, eeH.y); \
        const float s6 = fmaf(-2.f, aH##i.z, eeH.z); \
        const float s7 = fmaf(-2.f, aH##i.w, eeH.w); \
        unsigned long long m = pack_score(s0, kL), t; \
        t = pack_score(s1, kL + 1); if (t < m) m = t; \
        t = pack_score(s2, kL + 2); if (t < m) m = t; \
        t = pack_score(s3, kL + 3); if (t < m) m = t; \
        t = pack_score(s4, kH);     if (t < m) m = t; \
        t = pack_score(s5, kH + 1); if (t < m) m = t; \
        t = pack_score(s6, kH + 2); if (t < m) m = t; \
        t = pack_score(s7, kH + 3); if (t < m) m = t; \
        for (int off = 32; off > 0; off >>= 1) { \
            unsigned long long o = __shfl_down(m, off, 64); \
            if (o < m) m = o; \
        } \
        if (ln == 0) red[wv][i] = m; }
    RED_P(0) RED_P(1) RED_P(2) RED_P(3)
    RED_P(4) RED_P(5) RED_P(6) RED_P(7)
#undef RED_P

    __syncthreads();
    if (tid < P_TILE) {
        unsigned long long m = red[0][tid];
        if (red[1][tid] < m) m = red[1][tid];
        const int k = (int)(unsigned int)(m & 0xFFFFFFFFull);
        ksel[tid] = k;
        out_idx[n0 + tid] = (float)k;
        atomicAdd(counts + k, 1u);   // overlapped global histogram (r7/r11-proven)
    }
    __syncthreads();

    // fused quantize + loss: 128 threads -> (c = tid>>1, 4 pixels); x from LDS
    {
        const int c  = tid >> 1;
        const int pb = (tid & 1) * 4;
        float ls = 0.f;
        float4 qv;
        float* qvp = &qv.x;
#pragma unroll
        for (int j = 0; j < 4; ++j) {
            const int k = ksel[pb + j];
            const float q  = embed[c * K_EMB + k];  // gather, L2-resident table
            const float xv = x_lds[c * P_TILE + pb + j];
            const float d  = q - xv;
            ls = fmaf(d, d, ls);
            qvp[j] = q;
        }
        *reinterpret_cast<float4*>(out_q + b * (C_DIM * HW) + c * HW + hw0 + pb) = qv;
        for (int off = 32; off > 0; off >>= 1) ls += __shfl_down(ls, off, 64);
        if (ln == 0) lred[wv] = ls;
    }
    __syncthreads();
    if (tid == 0) atomicAdd(lossAcc, lred[0] + lred[1]);  // 1 atomic per block
}

__global__ __launch_bounds__(1024) void k_scalar(
    const unsigned int* __restrict__ counts, const float* __restrict__ lossAcc,
    float* __restrict__ out_loss, float* __restrict__ out_perp) {
    __shared__ float red[16];
    const int tid = threadIdx.x;  // 0..1023
    float p = (float)counts[tid] * (1.0f / (float)N_PIX);
    float t = p * logf(p + 1e-10f);   // p==0 -> exactly 0, matches reference
    for (int off = 32; off > 0; off >>= 1) t += __shfl_down(t, off, 64);
    if ((tid & 63) == 0) red[tid >> 6] = t;
    __syncthreads();
    if (tid == 0) {
        float s = 0.f;
#pragma unroll
        for (int i = 0; i < 16; ++i) s += red[i];
        *out_perp = expf(-s);
        *out_loss = 0.25f * (*lossAcc) * (1.0f / (float)(N_PIX * C_DIM));
    }
}

extern "C" void kernel_launch(void* const* d_in, const int* in_sizes, int n_in,
                              void* d_out, int out_size, void* d_ws, size_t ws_size,
                              hipStream_t stream) {
    const float* inp   = (const float*)d_in[0];
    const float* embed = (const float*)d_in[1];
    float* out = (float*)d_out;

    char* ws = (char*)d_ws;
    unsigned int* counts  = (unsigned int*)(ws + 0);
    float*        lossAcc = (float*)(ws + 4096);
    float*        e2      = (float*)(ws + 8192);

    hipMemsetAsync(ws, 0, 4104, stream);  // counts + lossAcc

    k_e2<<<dim3(K_EMB / 256), dim3(256), 0, stream>>>(embed, e2);
    k_main<<<dim3(NBLK), dim3(128), 0, stream>>>(
        inp, embed, e2, counts, lossAcc, out + OUT_Q_OFF, out + OUT_IDX_OFF);
    k_scalar<<<dim3(1), dim3(1024), 0, stream>>>(counts, lossAcc,
        out + OUT_LOSS_OFF, out + OUT_PERP_OFF);
}